// Round 12
// baseline (411.269 us; speedup 1.0000x reference)
//
#include <hip/hip_runtime.h>
#include <cstdint>

typedef __bf16 bf16_t;
typedef bf16_t bf16x8 __attribute__((ext_vector_type(8)));
typedef bf16_t bf16x4 __attribute__((ext_vector_type(4)));
typedef float  floatx4 __attribute__((ext_vector_type(4)));

// async global->LDS, 16B per lane; LDS dest = wave-uniform base + lane*16
#define GLD_LDS(g, l) __builtin_amdgcn_global_load_lds( \
    (const __attribute__((address_space(1))) unsigned int*)(g), \
    (__attribute__((address_space(3))) unsigned int*)(l), 16, 0, 0)

#define MFMA_BF16_16x16x32 __builtin_amdgcn_mfma_f32_16x16x32_bf16

// ---------------- fused weight prep ----------------
__global__ __launch_bounds__(256) void prep(
    const float* __restrict__ wq, const float* __restrict__ wk,
    const float* __restrict__ wv, const float* __restrict__ w1,
    const float* __restrict__ w2, const float* __restrict__ bq,
    const float* __restrict__ bk,
    bf16_t* __restrict__ wqk_hi, bf16_t* __restrict__ wqk_lo,
    bf16_t* __restrict__ wvb, bf16_t* __restrict__ w1b, bf16_t* __restrict__ w2b,
    float* __restrict__ bqk) {
  const int blk = blockIdx.x, tid = threadIdx.x;
  if (blk < 2048) {                       // wq / wk split
    const int qk = blk >> 10;             // 0 = q, 1 = k
    const int i  = (blk & 1023) * 256 + tid;
    const float* src = qk ? wk : wq;
    float4 v = ((const float4*)src)[i];
    float f[4] = {v.x, v.y, v.z, v.w};
    bf16x4 h, l;
    #pragma unroll
    for (int j = 0; j < 4; ++j) { h[j] = (bf16_t)f[j]; l[j] = (bf16_t)(f[j] - (float)h[j]); }
    ((bf16x4*)(wqk_hi + qk * 1024 * 1024))[i] = h;
    ((bf16x4*)(wqk_lo + qk * 1024 * 1024))[i] = l;
  } else if (blk < 3072) {                // wv cast
    const int i = (blk - 2048) * 256 + tid;
    float4 v = ((const float4*)wv)[i];
    bf16x4 o; o[0]=(bf16_t)v.x; o[1]=(bf16_t)v.y; o[2]=(bf16_t)v.z; o[3]=(bf16_t)v.w;
    ((bf16x4*)wvb)[i] = o;
  } else if (blk < 7168) {                // w1 cast
    const int i = (blk - 3072) * 256 + tid;
    float4 v = ((const float4*)w1)[i];
    bf16x4 o; o[0]=(bf16_t)v.x; o[1]=(bf16_t)v.y; o[2]=(bf16_t)v.z; o[3]=(bf16_t)v.w;
    ((bf16x4*)w1b)[i] = o;
  } else if (blk < 11264) {               // w2 cast
    const int i = (blk - 7168) * 256 + tid;
    float4 v = ((const float4*)w2)[i];
    bf16x4 o; o[0]=(bf16_t)v.x; o[1]=(bf16_t)v.y; o[2]=(bf16_t)v.z; o[3]=(bf16_t)v.w;
    ((bf16x4*)w2b)[i] = o;
  } else {                                // bias concat
    const int i = (blk - 11264) * 256 + tid;
    if (i < 1024) { bqk[i] = bq[i]; bqk[1024 + i] = bk[i]; }
  }
}

// ---------------- LN helpers ----------------

__device__ __forceinline__ void block_sum2(float& s, float& ss, float* red) {
  #pragma unroll
  for (int off = 32; off > 0; off >>= 1) {
    s  += __shfl_down(s, off);
    ss += __shfl_down(ss, off);
  }
  const int wave = threadIdx.x >> 6;
  if ((threadIdx.x & 63) == 0) { red[wave * 2] = s; red[wave * 2 + 1] = ss; }
  __syncthreads();
  s  = red[0] + red[2] + red[4] + red[6];
  ss = red[1] + red[3] + red[5] + red[7];
}

// LN over D=1024, fp32 in -> hi/lo bf16 out.
__global__ __launch_bounds__(256) void ln_fwd_split(const float* __restrict__ x,
    const float* __restrict__ g, const float* __restrict__ b,
    bf16_t* __restrict__ out_hi, bf16_t* __restrict__ out_lo) {
  __shared__ float red[8];
  const size_t row = blockIdx.x;
  float4 v = ((const float4*)(x + row * 1024))[threadIdx.x];
  float s  = v.x + v.y + v.z + v.w;
  float ss = v.x*v.x + v.y*v.y + v.z*v.z + v.w*v.w;
  block_sum2(s, ss, red);
  const float mu  = s * (1.f / 1024.f);
  const float var = ss * (1.f / 1024.f) - mu * mu;
  const float rs  = rsqrtf(var + 1e-5f);
  float4 gg = ((const float4*)g)[threadIdx.x];
  float4 bb = ((const float4*)b)[threadIdx.x];
  float f[4];
  f[0] = (v.x - mu) * rs * gg.x + bb.x;
  f[1] = (v.y - mu) * rs * gg.y + bb.y;
  f[2] = (v.z - mu) * rs * gg.z + bb.z;
  f[3] = (v.w - mu) * rs * gg.w + bb.w;
  bf16x4 oh, ol;
  #pragma unroll
  for (int j = 0; j < 4; ++j) {
    oh[j] = (bf16_t)f[j];
    ol[j] = (bf16_t)(f[j] - (float)oh[j]);
  }
  ((bf16x4*)(out_hi + row * 1024))[threadIdx.x] = oh;
  ((bf16x4*)(out_lo + row * 1024))[threadIdx.x] = ol;
}

// t = x + attn; LN(t) -> bf16. (no second residual in reference)
__global__ __launch_bounds__(256) void resid_ln_fwd(const float* __restrict__ x,
    const float* __restrict__ a, const float* __restrict__ g, const float* __restrict__ b,
    bf16_t* __restrict__ out) {
  __shared__ float red[8];
  const size_t row = blockIdx.x;
  float4 v = ((const float4*)(x + row * 1024))[threadIdx.x];
  float4 av = ((const float4*)(a + row * 1024))[threadIdx.x];
  v.x += av.x; v.y += av.y; v.z += av.z; v.w += av.w;
  float s  = v.x + v.y + v.z + v.w;
  float ss = v.x*v.x + v.y*v.y + v.z*v.z + v.w*v.w;
  block_sum2(s, ss, red);
  const float mu  = s * (1.f / 1024.f);
  const float var = ss * (1.f / 1024.f) - mu * mu;
  const float rs  = rsqrtf(var + 1e-5f);
  float4 gg = ((const float4*)g)[threadIdx.x];
  float4 bb = ((const float4*)b)[threadIdx.x];
  bf16x4 o;
  o[0] = (bf16_t)((v.x - mu) * rs * gg.x + bb.x);
  o[1] = (bf16_t)((v.y - mu) * rs * gg.y + bb.y);
  o[2] = (bf16_t)((v.z - mu) * rs * gg.z + bb.z);
  o[3] = (bf16_t)((v.w - mu) * rs * gg.w + bb.w);
  ((bf16x4*)(out + row * 1024))[threadIdx.x] = o;
}

// LN over F=4096 + ReLU, bf16 in-place. 16 elems/thread.
__global__ __launch_bounds__(256) void ln_relu_inplace(bf16_t* __restrict__ m,
    const float* __restrict__ g, const float* __restrict__ b) {
  __shared__ float red[8];
  const size_t row = blockIdx.x;
  bf16_t* mr = m + row * 4096;
  const int base = threadIdx.x * 16;
  bf16x8 v0 = *(bf16x8*)(mr + base);
  bf16x8 v1 = *(bf16x8*)(mr + base + 8);
  float f[16];
  #pragma unroll
  for (int i = 0; i < 8; ++i) { f[i] = (float)v0[i]; f[8 + i] = (float)v1[i]; }
  float s = 0.f, ss = 0.f;
  #pragma unroll
  for (int i = 0; i < 16; ++i) { s += f[i]; ss += f[i] * f[i]; }
  block_sum2(s, ss, red);
  const float mu  = s * (1.f / 4096.f);
  const float var = ss * (1.f / 4096.f) - mu * mu;
  const float rs  = rsqrtf(var + 1e-5f);
  bf16x8 o0, o1;
  #pragma unroll
  for (int i = 0; i < 16; ++i) {
    float ov = (f[i] - mu) * rs * g[base + i] + b[base + i];
    ov = fmaxf(ov, 0.f);
    if (i < 8) o0[i] = (bf16_t)ov; else o1[i - 8] = (bf16_t)ov;
  }
  *(bf16x8*)(mr + base) = o0;
  *(bf16x8*)(mr + base + 8) = o1;
}

// 2D-chunked XCD swizzle (R6, kept: FETCH 135->49MB on MLP2): XCD x owns
// bx in [x*gx/8, (x+1)*gx/8), iterating by outer. Requires gx % 8 == 0.
__device__ __forceinline__ void xcd_chunk2d(int& bx, int& by) {
  const int gx = gridDim.x;
  const int f  = (int)(blockIdx.y * gx + blockIdx.x);
  const int xcd = f & 7;
  const int i = f >> 3;
  const int bxPer = gx >> 3;
  by = i / bxPer;
  bx = xcd * bxPer + (i - by * bxPer);
}

// ---------------- GEMM: C[M,N] = A[M,K] * B[N,K]^T + bias ----------------
// BM x 128 tile, 4 waves (2x2), 16x16x32 bf16 MFMA.
// BK=64 (R10/R11, all gemm_bt now): single-buffer, 16*MI MFMA per
// barrier-pair (halves stage/barrier overhead per FLOP) + XOR-chunk
// swizzle (chunk ^= row&7, 8 chunks/row) = min-cycle LDS banking for
// every ds_read_b128 (linear [BM][32/64] was 8-way conflicted). Swizzle
// applied on per-lane GLOBAL source (gload_lds dest stays linear, rule
// #21); XOR permutes chunks within a row -> source stays 128B-coalesced.
// Read: chunk = (quad+4*kk) ^ (l15&7)  (row&7 == l15&7: wm,i*16 ≡ 0 mod 8).
// BK=32 path retained (R9 dbuf) but unused.
// OUT_MODE: 0 = fp32 row-major, 1 = bf16 row-major,
//           3 = bf16 V^T direct [bh][e][2048] (fused transpose_v)
// SK: split-K (blockIdx.z); SK>1 -> fp32 atomicAdd, bias in slice 0.
template <int OUT_MODE, int BM, int SK, int BK>
__global__ __launch_bounds__(256) void gemm_bt(
    const bf16_t* __restrict__ A, const bf16_t* __restrict__ Bw,
    const float* __restrict__ bias, void* __restrict__ Cp,
    int M, int N, int K) {
  constexpr int MI = BM / 32;             // acc i-extent per wave
  constexpr bool DB = (BK == 32);         // double-buffer only BK=32 path
  constexpr int ASZ = BM * BK;
  constexpr int BSZ = 128 * BK;
  __shared__ bf16_t As[(DB ? 2 : 1) * ASZ];
  __shared__ bf16_t Bs[(DB ? 2 : 1) * BSZ];
  const int tid  = threadIdx.x;
  const int wave = tid >> 6, lane = tid & 63;
  const int quad = lane >> 4, l15 = lane & 15;
  int bx = blockIdx.x, by = blockIdx.y;
  xcd_chunk2d(bx, by);
  const int m0 = bx * BM, n0 = by * 128;
  const int wm = (wave >> 1) * (BM / 2), wn = (wave & 1) * 64;
  const int ks = (SK > 1) ? (int)blockIdx.z : 0;
  const int kbeg = ks * (K / SK), kend = kbeg + K / SK;

  floatx4 acc[MI][4] = {};

  if constexpr (BK == 32) {
    const int srowA = wave * (BM / 4) + (lane >> 2);
    const int srowB = wave * 32 + (lane >> 2);
    const int scol = (lane & 3) * 8;
    const bf16_t* Ag = A  + (size_t)(m0 + srowA) * K + scol;
    const bf16_t* Bg = Bw + (size_t)(n0 + srowB) * K + scol;
    auto stage = [&](int buf, int k0) {
      #pragma unroll
      for (int i = 0; i < BM / 64; ++i)
        GLD_LDS(Ag + (size_t)(i * 16) * K + k0,
                As + buf * ASZ + wave * (BM / 4) * 32 + i * 512);
      #pragma unroll
      for (int i = 0; i < 2; ++i)
        GLD_LDS(Bg + (size_t)(i * 16) * K + k0,
                Bs + buf * BSZ + wave * 1024 + i * 512);
    };
    stage(0, kbeg);
    __syncthreads();
    int cur = 0;
    for (int k0 = kbeg; k0 < kend; k0 += 32) {
      if (k0 + 32 < kend) stage(cur ^ 1, k0 + 32);
      bf16x8 af[MI], bfr[4];
      #pragma unroll
      for (int i = 0; i < MI; ++i)
        af[i] = *(const bf16x8*)(As + cur * ASZ + (wm + i * 16 + l15) * 32 + quad * 8);
      #pragma unroll
      for (int j = 0; j < 4; ++j)
        bfr[j] = *(const bf16x8*)(Bs + cur * BSZ + (wn + j * 16 + l15) * 32 + quad * 8);
      #pragma unroll
      for (int i = 0; i < MI; ++i)
        #pragma unroll
        for (int j = 0; j < 4; ++j)
          acc[i][j] = MFMA_BF16_16x16x32(af[i], bfr[j], acc[i][j], 0, 0, 0);
      __syncthreads();
      cur ^= 1;
    }
  } else {
    // BK=64 single-buffer, swizzled
    for (int k0 = kbeg; k0 < kend; k0 += 64) {
      __syncthreads();                    // all waves done reading prev tile
      #pragma unroll
      for (int i = 0; i < BM / 32; ++i) { // A: BM/4 rows/wave x 8 chunks
        const int flat = i * 64 + lane;
        const int rl = flat >> 3, ch = flat & 7;
        GLD_LDS(A + (size_t)(m0 + wave * (BM / 4) + rl) * K + k0 + ((ch ^ (rl & 7)) * 8),
                As + wave * (BM / 4) * 64 + i * 512);
      }
      #pragma unroll
      for (int i = 0; i < 4; ++i) {       // B: 32 rows/wave x 8 chunks
        const int flat = i * 64 + lane;
        const int rl = flat >> 3, ch = flat & 7;
        GLD_LDS(Bw + (size_t)(n0 + wave * 32 + rl) * K + k0 + ((ch ^ (rl & 7)) * 8),
                Bs + wave * 32 * 64 + i * 512);
      }
      __syncthreads();                    // drains vmcnt(0): tile resident
      #pragma unroll
      for (int kk = 0; kk < 2; ++kk) {
        const int co = ((quad + 4 * kk) ^ (l15 & 7)) * 8;
        bf16x8 af[MI], bfr[4];
        #pragma unroll
        for (int i = 0; i < MI; ++i)
          af[i] = *(const bf16x8*)(As + (wm + i * 16 + l15) * 64 + co);
        #pragma unroll
        for (int j = 0; j < 4; ++j)
          bfr[j] = *(const bf16x8*)(Bs + (wn + j * 16 + l15) * 64 + co);
        #pragma unroll
        for (int i = 0; i < MI; ++i)
          #pragma unroll
          for (int j = 0; j < 4; ++j)
            acc[i][j] = MFMA_BF16_16x16x32(af[i], bfr[j], acc[i][j], 0, 0, 0);
      }
    }
  }

  if (OUT_MODE == 3) {                    // fused V^T epilogue
    #pragma unroll
    for (int j = 0; j < 4; ++j) {
      const int col = n0 + wn + j * 16 + l15;
      const float bv = bias[col];
      const int h = col >> 6, e = col & 63;
      #pragma unroll
      for (int i = 0; i < MI; ++i) {
        const int row0 = m0 + wm + i * 16 + quad * 4;
        const int b = row0 >> 11, n = row0 & 2047;
        bf16x4 o;
        #pragma unroll
        for (int r = 0; r < 4; ++r) o[r] = (bf16_t)(acc[i][j][r] + bv);
        *(bf16x4*)((bf16_t*)Cp + ((size_t)((b << 4) + h) * 64 + e) * 2048 + n) = o;
      }
    }
    return;
  }
  #pragma unroll
  for (int j = 0; j < 4; ++j) {
    const int col = n0 + wn + j * 16 + l15;
    const float bv = (SK == 1 || ks == 0) ? bias[col] : 0.f;
    #pragma unroll
    for (int i = 0; i < MI; ++i) {
      #pragma unroll
      for (int r = 0; r < 4; ++r) {
        const int row = m0 + wm + i * 16 + quad * 4 + r;
        const float v = acc[i][j][r] + bv;
        if (OUT_MODE == 0) {
          if (SK > 1) atomicAdd(&((float*)Cp)[(size_t)row * N + col], v);
          else        ((float*)Cp)[(size_t)row * N + col] = v;
        } else if (OUT_MODE == 1) {
          ((bf16_t*)Cp)[(size_t)row * N + col] = (bf16_t)v;
        }
      }
    }
  }
}

// Split-precision GEMM for q,k: 3-term bf16 emulation of fp32.
// 64x128 tile. R11: BK=64 single-buffer + XOR-chunk swizzle (R10 recipe,
// proven on gemm_bt): 48 MFMA per barrier-pair (was 24) and min-cycle
// LDS banking (was 8-way conflicted -> the constant 6.29M counter).
// LDS 48KB -> 3 blocks/CU, matching measured effective occupancy (33%).
// Writes q (cols<1024, scaled by 32=sqrt(D)) and k head-major, hi/lo.
__global__ __launch_bounds__(256) void gemm_qk_split(
    const bf16_t* __restrict__ Ah, const bf16_t* __restrict__ Al,
    const bf16_t* __restrict__ Bh, const bf16_t* __restrict__ Bl,
    const float* __restrict__ bias,
    bf16_t* __restrict__ qhi, bf16_t* __restrict__ qlo,
    bf16_t* __restrict__ khi, bf16_t* __restrict__ klo,
    int M, int N, int K) {
  __shared__ bf16_t Ash[64 * 64];
  __shared__ bf16_t Asl[64 * 64];
  __shared__ bf16_t Bsh[128 * 64];
  __shared__ bf16_t Bsl[128 * 64];
  const int tid  = threadIdx.x;
  const int wave = tid >> 6, lane = tid & 63;
  const int quad = lane >> 4, l15 = lane & 15;
  int bx = blockIdx.x, by = blockIdx.y;
  xcd_chunk2d(bx, by);
  const int m0 = bx * 64, n0 = by * 128;
  const int wm = (wave >> 1) * 32, wn = (wave & 1) * 64;

  floatx4 acc[2][4] = {};

  for (int k0 = 0; k0 < K; k0 += 64) {
    __syncthreads();                      // all waves done reading prev tile
    #pragma unroll
    for (int i = 0; i < 2; ++i) {         // A: 16 rows/wave x 8 chunks, hi+lo
      const int flat = i * 64 + lane;
      const int rl = flat >> 3, ch = flat & 7;
      const size_t off = (size_t)(m0 + wave * 16 + rl) * K + k0 + ((ch ^ (rl & 7)) * 8);
      GLD_LDS(Ah + off, Ash + wave * 16 * 64 + i * 512);
      GLD_LDS(Al + off, Asl + wave * 16 * 64 + i * 512);
    }
    #pragma unroll
    for (int i = 0; i < 4; ++i) {         // B: 32 rows/wave x 8 chunks, hi+lo
      const int flat = i * 64 + lane;
      const int rl = flat >> 3, ch = flat & 7;
      const size_t off = (size_t)(n0 + wave * 32 + rl) * K + k0 + ((ch ^ (rl & 7)) * 8);
      GLD_LDS(Bh + off, Bsh + wave * 32 * 64 + i * 512);
      GLD_LDS(Bl + off, Bsl + wave * 32 * 64 + i * 512);
    }
    __syncthreads();                      // drains vmcnt(0): tile resident
    #pragma unroll
    for (int kk = 0; kk < 2; ++kk) {
      const int co = ((quad + 4 * kk) ^ (l15 & 7)) * 8;
      bf16x8 ah[2], al[2], bh[4], bl[4];
      #pragma unroll
      for (int i = 0; i < 2; ++i) {
        const int ro = (wm + i * 16 + l15) * 64 + co;
        ah[i] = *(const bf16x8*)(Ash + ro);
        al[i] = *(const bf16x8*)(Asl + ro);
      }
      #pragma unroll
      for (int j = 0; j < 4; ++j) {
        const int ro = (wn + j * 16 + l15) * 64 + co;
        bh[j] = *(const bf16x8*)(Bsh + ro);
        bl[j] = *(const bf16x8*)(Bsl + ro);
      }
      #pragma unroll
      for (int i = 0; i < 2; ++i)
        #pragma unroll
        for (int j = 0; j < 4; ++j) {
          acc[i][j] = MFMA_BF16_16x16x32(ah[i], bh[j], acc[i][j], 0, 0, 0);
          acc[i][j] = MFMA_BF16_16x16x32(ah[i], bl[j], acc[i][j], 0, 0, 0);
          acc[i][j] = MFMA_BF16_16x16x32(al[i], bh[j], acc[i][j], 0, 0, 0);
        }
    }
  }
  #pragma unroll
  for (int j = 0; j < 4; ++j) {
    const int col = n0 + wn + j * 16 + l15;       // [0,2048)
    const float bv = bias[col];
    const bool isq = col < 1024;
    bf16_t* hib = isq ? qhi : khi;
    bf16_t* lob = isq ? qlo : klo;
    const float scale = isq ? 32.0f : 1.0f;       // sqrt(D) folded into q
    const int h = (col >> 6) & 15, e = col & 63;
    #pragma unroll
    for (int i = 0; i < 2; ++i) {
      #pragma unroll
      for (int r = 0; r < 4; ++r) {
        const int row = m0 + wm + i * 16 + quad * 4 + r;
        const int b = row >> 11, n = row & 2047;
        const float c = (acc[i][j][r] + bv) * scale;
        const bf16_t chi = (bf16_t)c;
        const bf16_t clo = (bf16_t)(c - (float)chi);
        const size_t dst = (((size_t)((b << 4) + h) * 2048 + n) << 6) + e;
        hib[dst] = chi;
        lob[dst] = clo;
      }
    }
  }
}

// ---------------- causal flash attention ----------------
// (unchanged from R5: swizzled 32KB LDS, (256,4), setprio)
#define SWZ(row, chunk) (((row) << 6) + ((((chunk) ^ ((row) & 7))) << 3))
__global__ __launch_bounds__(256, 4) void attn_causal(
    const bf16_t* __restrict__ qhi, const bf16_t* __restrict__ qlo,
    const bf16_t* __restrict__ khi, const bf16_t* __restrict__ klo,
    const bf16_t* __restrict__ vT, float* __restrict__ o) {
  __shared__ bf16_t KsH[64 * 64];     // [key][e], swizzled
  __shared__ bf16_t KsL[64 * 64];
  __shared__ bf16_t Vt[64 * 64];      // [e][key], swizzled
  __shared__ bf16_t Ps[4][16 * 64];   // per-wave P, rows=q (16), swizzled

  const int tid  = threadIdx.x;
  const int wave = tid >> 6, lane = tid & 63;
  const int quad = lane >> 4, l15 = lane & 15;
  const int bh = blockIdx.x;
  const int q0 = (31 - (int)blockIdx.y) * 64;    // heavy blocks first
  const size_t hb = (size_t)bh * 2048;

  // Q fragments: rows wmin+l15 (A/B-layout: row=l15, k=quad*8+j)
  const int wmin = q0 + wave * 16;
  const int qrow = wmin + l15;                   // this lane's q-row
  bf16x8 qh[2], ql[2];
  {
    const bf16_t* qbh = qhi + ((hb + wmin + l15) << 6) + quad * 8;
    const bf16_t* qbl = qlo + ((hb + wmin + l15) << 6) + quad * 8;
    qh[0] = *(const bf16x8*)qbh;
    qh[1] = *(const bf16x8*)(qbh + 32);
    ql[0] = *(const bf16x8*)qbl;
    ql[1] = *(const bf16x8*)(qbl + 32);
  }

  floatx4 accO[4] = {};                // O[q=quad*4+r][e=j*16+l15]
  float m_row = -1e30f;                // running max for q-row (wmin+l15)
  float l_row = 0.f;                   // running denom for q-row (wmin+l15)

  // staging geometry: wave w covers rows [16w,16w+16) of K / e-rows of V^T
  const int kr = wave * 16 + (lane >> 3);     // + {0,8}
  const int kc7 = lane & 7;                   // 16B chunk index 0..7
  const bf16_t* kgh = khi + ((hb + kr) << 6) + kc7 * 8;
  const bf16_t* kgl = klo + ((hb + kr) << 6) + kc7 * 8;
  const bf16_t* vg  = vT + ((size_t)(bh * 64 + kr)) * 2048 + kc7 * 8;

  // prefetch tile 0
  bf16x8 pkh0 = *(const bf16x8*)(kgh);
  bf16x8 pkh1 = *(const bf16x8*)(kgh + (8 << 6));
  bf16x8 pkl0 = *(const bf16x8*)(kgl);
  bf16x8 pkl1 = *(const bf16x8*)(kgl + (8 << 6));
  bf16x8 pv0  = *(const bf16x8*)(vg);
  bf16x8 pv1  = *(const bf16x8*)(vg + 8 * 2048);

  const int ntiles = (q0 >> 6) + 1;
  for (int t = 0; t < ntiles; ++t) {
    const int k0 = t * 64;
    __syncthreads();                          // all waves done reading prev LDS
    *(bf16x8*)(KsH + SWZ(kr, kc7))     = pkh0;
    *(bf16x8*)(KsH + SWZ(kr + 8, kc7)) = pkh1;
    *(bf16x8*)(KsL + SWZ(kr, kc7))     = pkl0;
    *(bf16x8*)(KsL + SWZ(kr + 8, kc7)) = pkl1;
    *(bf16x8*)(Vt  + SWZ(kr, kc7))     = pv0;
    *(bf16x8*)(Vt  + SWZ(kr + 8, kc7)) = pv1;
    if (t + 1 < ntiles) {                     // prefetch next tile
      const int koff = (t + 1) << 12;         // 64 rows * 64 el (K layout)
      pkh0 = *(const bf16x8*)(kgh + koff);
      pkh1 = *(const bf16x8*)(kgh + koff + (8 << 6));
      pkl0 = *(const bf16x8*)(kgl + koff);
      pkl1 = *(const bf16x8*)(kgl + koff + (8 << 6));
      pv0  = *(const bf16x8*)(vg + (t + 1) * 64);
      pv1  = *(const bf16x8*)(vg + (t + 1) * 64 + 8 * 2048);
    }
    __syncthreads();                          // staging visible

    const bool needmask = (k0 + 63 > wmin);

    // S^T = K Q^T (split 3-term): lane holds S[key=k0+j*16+quad*4+r][qrow]
    floatx4 sv[4];
    __builtin_amdgcn_s_setprio(1);
    #pragma unroll
    for (int j = 0; j < 4; ++j) {
      const int rK = j * 16 + l15;
      const bf16x8 kh0 = *(const bf16x8*)(KsH + SWZ(rK, quad));
      const bf16x8 kh1 = *(const bf16x8*)(KsH + SWZ(rK, quad + 4));
      const bf16x8 kl0 = *(const bf16x8*)(KsL + SWZ(rK, quad));
      const bf16x8 kl1 = *(const bf16x8*)(KsL + SWZ(rK, quad + 4));
      floatx4 acc = {};
      acc = MFMA_BF16_16x16x32(kh0, qh[0], acc, 0, 0, 0);
      acc = MFMA_BF16_16x16x32(kh1, qh[1], acc, 0, 0, 0);
      acc = MFMA_BF16_16x16x32(kl0, qh[0], acc, 0, 0, 0);
      acc = MFMA_BF16_16x16x32(kl1, qh[1], acc, 0, 0, 0);
      acc = MFMA_BF16_16x16x32(kh0, ql[0], acc, 0, 0, 0);
      acc = MFMA_BF16_16x16x32(kh1, ql[1], acc, 0, 0, 0);
      sv[j] = acc;
    }
    __builtin_amdgcn_s_setprio(0);

    // in-lane softmax for q-row (wmin+l15); keys j*16+quad*4+r
    const int lim = qrow - k0 - quad * 4;     // mask if j*16+r > lim
    float mr = -1e30f;
    #pragma unroll
    for (int j = 0; j < 4; ++j)
      #pragma unroll
      for (int r = 0; r < 4; ++r) {
        float x = sv[j][r];
        if (needmask && (j * 16 + r > lim)) x = -1e30f;
        sv[j][r] = x;
        mr = fmaxf(mr, x);
      }
    mr = fmaxf(mr, __shfl_xor(mr, 16));       // reduce across quads
    mr = fmaxf(mr, __shfl_xor(mr, 32));
    const float mold = m_row;
    const float mnew = fmaxf(mold, mr);
    m_row = mnew;
    float psum = 0.f;
    bf16x4 pb[4];
    #pragma unroll
    for (int j = 0; j < 4; ++j)
      #pragma unroll
      for (int r = 0; r < 4; ++r) {
        const float p = __expf(sv[j][r] - mnew);
        const bf16_t pv = (bf16_t)p;
        psum += (float)pv;                    // denom matches bf16 numerator
        pb[j][r] = pv;
      }
    // write P^T -> A-layout rows: Ps[qlocal=l15][key j*16+quad*4 .. +3]
    {
      bf16_t* pw = &Ps[wave][0];
      #pragma unroll
      for (int j = 0; j < 4; ++j)
        *(bf16x4*)(pw + SWZ(l15, 2 * j + (quad >> 1)) + (quad & 1) * 4) = pb[j];
    }
    psum += __shfl_xor(psum, 16);
    psum += __shfl_xor(psum, 32);
    const float alpha = __expf(mold - mnew);  // ==1 when no max growth
    l_row = l_row * alpha + psum;
    if (__any(mnew > mold)) {                 // defer-rescale when max static
      #pragma unroll
      for (int r = 0; r < 4; ++r) {
        const float ar = __shfl(alpha, quad * 4 + r);  // alpha of row quad*4+r
        #pragma unroll
        for (int j = 0; j < 4; ++j) accO[j][r] *= ar;
      }
    }
    // Ps is wave-private: LDS completion is enough, no block barrier
    asm volatile("s_waitcnt lgkmcnt(0)" ::: "memory");
    __builtin_amdgcn_sched_barrier(0);

    // O += P V   (P: A-layout rows l15; V^T: B-layout from Vt)
    bf16x8 pf[2];
    {
      const bf16_t* pw = &Ps[wave][0];
      pf[0] = *(const bf16x8*)(pw + SWZ(l15, quad));
      pf[1] = *(const bf16x8*)(pw + SWZ(l15, quad + 4));
    }
    __builtin_amdgcn_s_setprio(1);
    #pragma unroll
    for (int j = 0; j < 4; ++j) {
      const int rV = j * 16 + l15;
      const bf16x8 vf0 = *(const bf16x8*)(Vt + SWZ(rV, quad));
      const bf16x8 vf1 = *(const bf16x8*)(Vt + SWZ(rV, quad + 4));
      accO[j] = MFMA_BF16_16x16x32(pf[0], vf0, accO[j], 0, 0, 0);
      accO[j] = MFMA_BF16_16x16x32(pf[1], vf1, accO[j], 0, 0, 0);
    }
    __builtin_amdgcn_s_setprio(0);
  }

  // normalize + write (token-major fp32 for resid_ln)
  const int b = bh >> 4, h = bh & 15;
  #pragma unroll
  for (int r = 0; r < 4; ++r) {
    const float lr = __shfl(l_row, quad * 4 + r);  // denom of row quad*4+r
    const float linv = 1.f / lr;
    const int qr = wmin + quad * 4 + r;
    float* orow = o + ((size_t)(b * 2048) + qr) * 1024 + h * 64;
    #pragma unroll
    for (int j = 0; j < 4; ++j)
      orow[j * 16 + l15] = accO[j][r] * linv;
  }
}

// ---------------- launcher ----------------

extern "C" void kernel_launch(void* const* d_in, const int* in_sizes, int n_in,
                              void* d_out, int out_size, void* d_ws, size_t ws_size,
                              hipStream_t stream) {
  const float* x        = (const float*)d_in[0];
  const float* wq       = (const float*)d_in[1];
  const float* bq       = (const float*)d_in[2];
  const float* wk       = (const float*)d_in[3];
  const float* bk       = (const float*)d_in[4];
  const float* wv       = (const float*)d_in[5];
  const float* bv       = (const float*)d_in[6];
  const float* w1       = (const float*)d_in[7];
  const float* b1       = (const float*)d_in[8];
  const float* ln_mlp_g = (const float*)d_in[9];
  const float* ln_mlp_b = (const float*)d_in[10];
  const float* w2       = (const float*)d_in[11];
  const float* b2       = (const float*)d_in[12];
  const float* ln1_g    = (const float*)d_in[13];
  const float* ln1_b    = (const float*)d_in[14];
  const float* ln2_g    = (const float*)d_in[15];
  const float* ln2_b    = (const float*)d_in[16];

  char* ws = (char*)d_ws;
  bf16_t* h_hi   = (bf16_t*)(ws);                  // 8 MiB  [4096,1024]
  bf16_t* h_lo   = (bf16_t*)(ws + (8u  << 20));    // 8 MiB
  bf16_t* wqk_hi = (bf16_t*)(ws + (16u << 20));    // 4 MiB  [2048,1024]
  bf16_t* wqk_lo = (bf16_t*)(ws + (20u << 20));    // 4 MiB
  bf16_t* wvb    = (bf16_t*)(ws + (24u << 20));    // 2 MiB  [1024,1024]
  float*  bqk    = (float*) (ws + (26u << 20));    // 8 KiB  [2048]
  bf16_t* w1b    = (bf16_t*)(ws + (28u << 20));    // 8 MiB  [4096,1024]
  bf16_t* w2b    = (bf16_t*)(ws + (36u << 20));    // 8 MiB  [1024,4096]
  bf16_t* qhi    = (bf16_t*)(ws + (44u << 20));    // 8 MiB  [32,2048,64] head-major
  bf16_t* qlo    = (bf16_t*)(ws + (52u << 20));    // 8 MiB
  bf16_t* khi    = (bf16_t*)(ws + (60u << 20));    // 8 MiB
  bf16_t* klo    = (bf16_t*)(ws + (68u << 20));    // 8 MiB
  bf16_t* mbuf   = (bf16_t*)(ws + (44u << 20));    // 32 MiB [4096,4096] (aliases q/k; dead by MLP1)
  bf16_t* vTb    = (bf16_t*)(ws + (76u << 20));    // 8 MiB  [32,64,2048] V^T (written directly by gemm_bt<3>)
  float*  attnb  = (float*) (ws + (84u << 20));    // 16 MiB [4096,1024] fp32
  bf16_t* h2     = (bf16_t*)(ws + (100u << 20));   // 8 MiB  -> total 108 MiB

  // zero d_out for split-K atomic accumulation (capture-safe async memset)
  hipMemsetAsync(d_out, 0, (size_t)4096 * 1024 * sizeof(float), stream);

  prep<<<11268, 256, 0, stream>>>(wq, wk, wv, w1, w2, bq, bk,
                                  wqk_hi, wqk_lo, wvb, w1b, w2b, bqk);

  ln_fwd_split<<<4096, 256, 0, stream>>>(x, ln1_g, ln1_b, h_hi, h_lo);
  gemm_qk_split<<<dim3(64, 16), 256, 0, stream>>>(h_hi, h_lo, wqk_hi, wqk_lo, bqk,
                                                  qhi, qlo, khi, klo, 4096, 2048, 1024);
  gemm_bt<3, 64, 1, 64><<<dim3(64, 8), 256, 0, stream>>>(h_hi, wvb, bv, vTb, 4096, 1024, 1024);
  attn_causal<<<dim3(32, 32), 256, 0, stream>>>(qhi, qlo, khi, klo, vTb, attnb);
  resid_ln_fwd<<<4096, 256, 0, stream>>>(x, attnb, ln2_g, ln2_b, h2);
  gemm_bt<1, 128, 1, 64><<<dim3(32, 32), 256, 0, stream>>>(h2, w1b, b1, mbuf, 4096, 4096, 1024);
  ln_relu_inplace<<<4096, 256, 0, stream>>>(mbuf, ln_mlp_g, ln_mlp_b);
  gemm_bt<0, 64, 2, 64><<<dim3(64, 8, 2), 256, 0, stream>>>(mbuf, w2b, b2, d_out, 4096, 1024, 4096);

  (void)in_sizes; (void)n_in; (void)out_size; (void)ws_size;
}

// Round 13
// 400.254 us; speedup vs baseline: 1.0275x; 1.0275x over previous
//
#include <hip/hip_runtime.h>
#include <cstdint>

typedef __bf16 bf16_t;
typedef bf16_t bf16x8 __attribute__((ext_vector_type(8)));
typedef bf16_t bf16x4 __attribute__((ext_vector_type(4)));
typedef float  floatx4 __attribute__((ext_vector_type(4)));

// async global->LDS, 16B per lane; LDS dest = wave-uniform base + lane*16
#define GLD_LDS(g, l) __builtin_amdgcn_global_load_lds( \
    (const __attribute__((address_space(1))) unsigned int*)(g), \
    (__attribute__((address_space(3))) unsigned int*)(l), 16, 0, 0)

#define MFMA_BF16_16x16x32 __builtin_amdgcn_mfma_f32_16x16x32_bf16

// ---------------- fused weight prep ----------------
__global__ __launch_bounds__(256) void prep(
    const float* __restrict__ wq, const float* __restrict__ wk,
    const float* __restrict__ wv, const float* __restrict__ w1,
    const float* __restrict__ w2, const float* __restrict__ bq,
    const float* __restrict__ bk,
    bf16_t* __restrict__ wqk_hi, bf16_t* __restrict__ wqk_lo,
    bf16_t* __restrict__ wvb, bf16_t* __restrict__ w1b, bf16_t* __restrict__ w2b,
    float* __restrict__ bqk) {
  const int blk = blockIdx.x, tid = threadIdx.x;
  if (blk < 2048) {                       // wq / wk split
    const int qk = blk >> 10;             // 0 = q, 1 = k
    const int i  = (blk & 1023) * 256 + tid;
    const float* src = qk ? wk : wq;
    float4 v = ((const float4*)src)[i];
    float f[4] = {v.x, v.y, v.z, v.w};
    bf16x4 h, l;
    #pragma unroll
    for (int j = 0; j < 4; ++j) { h[j] = (bf16_t)f[j]; l[j] = (bf16_t)(f[j] - (float)h[j]); }
    ((bf16x4*)(wqk_hi + qk * 1024 * 1024))[i] = h;
    ((bf16x4*)(wqk_lo + qk * 1024 * 1024))[i] = l;
  } else if (blk < 3072) {                // wv cast
    const int i = (blk - 2048) * 256 + tid;
    float4 v = ((const float4*)wv)[i];
    bf16x4 o; o[0]=(bf16_t)v.x; o[1]=(bf16_t)v.y; o[2]=(bf16_t)v.z; o[3]=(bf16_t)v.w;
    ((bf16x4*)wvb)[i] = o;
  } else if (blk < 7168) {                // w1 cast
    const int i = (blk - 3072) * 256 + tid;
    float4 v = ((const float4*)w1)[i];
    bf16x4 o; o[0]=(bf16_t)v.x; o[1]=(bf16_t)v.y; o[2]=(bf16_t)v.z; o[3]=(bf16_t)v.w;
    ((bf16x4*)w1b)[i] = o;
  } else if (blk < 11264) {               // w2 cast
    const int i = (blk - 7168) * 256 + tid;
    float4 v = ((const float4*)w2)[i];
    bf16x4 o; o[0]=(bf16_t)v.x; o[1]=(bf16_t)v.y; o[2]=(bf16_t)v.z; o[3]=(bf16_t)v.w;
    ((bf16x4*)w2b)[i] = o;
  } else {                                // bias concat
    const int i = (blk - 11264) * 256 + tid;
    if (i < 1024) { bqk[i] = bq[i]; bqk[1024 + i] = bk[i]; }
  }
}

// ---------------- LN helpers ----------------

__device__ __forceinline__ void block_sum2(float& s, float& ss, float* red) {
  #pragma unroll
  for (int off = 32; off > 0; off >>= 1) {
    s  += __shfl_down(s, off);
    ss += __shfl_down(ss, off);
  }
  const int wave = threadIdx.x >> 6;
  if ((threadIdx.x & 63) == 0) { red[wave * 2] = s; red[wave * 2 + 1] = ss; }
  __syncthreads();
  s  = red[0] + red[2] + red[4] + red[6];
  ss = red[1] + red[3] + red[5] + red[7];
}

// LN over D=1024, fp32 in -> hi/lo bf16 out.
__global__ __launch_bounds__(256) void ln_fwd_split(const float* __restrict__ x,
    const float* __restrict__ g, const float* __restrict__ b,
    bf16_t* __restrict__ out_hi, bf16_t* __restrict__ out_lo) {
  __shared__ float red[8];
  const size_t row = blockIdx.x;
  float4 v = ((const float4*)(x + row * 1024))[threadIdx.x];
  float s  = v.x + v.y + v.z + v.w;
  float ss = v.x*v.x + v.y*v.y + v.z*v.z + v.w*v.w;
  block_sum2(s, ss, red);
  const float mu  = s * (1.f / 1024.f);
  const float var = ss * (1.f / 1024.f) - mu * mu;
  const float rs  = rsqrtf(var + 1e-5f);
  float4 gg = ((const float4*)g)[threadIdx.x];
  float4 bb = ((const float4*)b)[threadIdx.x];
  float f[4];
  f[0] = (v.x - mu) * rs * gg.x + bb.x;
  f[1] = (v.y - mu) * rs * gg.y + bb.y;
  f[2] = (v.z - mu) * rs * gg.z + bb.z;
  f[3] = (v.w - mu) * rs * gg.w + bb.w;
  bf16x4 oh, ol;
  #pragma unroll
  for (int j = 0; j < 4; ++j) {
    oh[j] = (bf16_t)f[j];
    ol[j] = (bf16_t)(f[j] - (float)oh[j]);
  }
  ((bf16x4*)(out_hi + row * 1024))[threadIdx.x] = oh;
  ((bf16x4*)(out_lo + row * 1024))[threadIdx.x] = ol;
}

// t = x + attn; LN(t) -> bf16. (no second residual in reference)
__global__ __launch_bounds__(256) void resid_ln_fwd(const float* __restrict__ x,
    const float* __restrict__ a, const float* __restrict__ g, const float* __restrict__ b,
    bf16_t* __restrict__ out) {
  __shared__ float red[8];
  const size_t row = blockIdx.x;
  float4 v = ((const float4*)(x + row * 1024))[threadIdx.x];
  float4 av = ((const float4*)(a + row * 1024))[threadIdx.x];
  v.x += av.x; v.y += av.y; v.z += av.z; v.w += av.w;
  float s  = v.x + v.y + v.z + v.w;
  float ss = v.x*v.x + v.y*v.y + v.z*v.z + v.w*v.w;
  block_sum2(s, ss, red);
  const float mu  = s * (1.f / 1024.f);
  const float var = ss * (1.f / 1024.f) - mu * mu;
  const float rs  = rsqrtf(var + 1e-5f);
  float4 gg = ((const float4*)g)[threadIdx.x];
  float4 bb = ((const float4*)b)[threadIdx.x];
  bf16x4 o;
  o[0] = (bf16_t)((v.x - mu) * rs * gg.x + bb.x);
  o[1] = (bf16_t)((v.y - mu) * rs * gg.y + bb.y);
  o[2] = (bf16_t)((v.z - mu) * rs * gg.z + bb.z);
  o[3] = (bf16_t)((v.w - mu) * rs * gg.w + bb.w);
  ((bf16x4*)(out + row * 1024))[threadIdx.x] = o;
}

// LN over F=4096 + ReLU, bf16 in-place. 16 elems/thread.
__global__ __launch_bounds__(256) void ln_relu_inplace(bf16_t* __restrict__ m,
    const float* __restrict__ g, const float* __restrict__ b) {
  __shared__ float red[8];
  const size_t row = blockIdx.x;
  bf16_t* mr = m + row * 4096;
  const int base = threadIdx.x * 16;
  bf16x8 v0 = *(bf16x8*)(mr + base);
  bf16x8 v1 = *(bf16x8*)(mr + base + 8);
  float f[16];
  #pragma unroll
  for (int i = 0; i < 8; ++i) { f[i] = (float)v0[i]; f[8 + i] = (float)v1[i]; }
  float s = 0.f, ss = 0.f;
  #pragma unroll
  for (int i = 0; i < 16; ++i) { s += f[i]; ss += f[i] * f[i]; }
  block_sum2(s, ss, red);
  const float mu  = s * (1.f / 4096.f);
  const float var = ss * (1.f / 4096.f) - mu * mu;
  const float rs  = rsqrtf(var + 1e-5f);
  bf16x8 o0, o1;
  #pragma unroll
  for (int i = 0; i < 16; ++i) {
    float ov = (f[i] - mu) * rs * g[base + i] + b[base + i];
    ov = fmaxf(ov, 0.f);
    if (i < 8) o0[i] = (bf16_t)ov; else o1[i - 8] = (bf16_t)ov;
  }
  *(bf16x8*)(mr + base) = o0;
  *(bf16x8*)(mr + base + 8) = o1;
}

// 2D-chunked XCD swizzle (R6, kept: FETCH 135->49MB on MLP2): XCD x owns
// bx in [x*gx/8, (x+1)*gx/8), iterating by outer. Requires gx % 8 == 0.
__device__ __forceinline__ void xcd_chunk2d(int& bx, int& by) {
  const int gx = gridDim.x;
  const int f  = (int)(blockIdx.y * gx + blockIdx.x);
  const int xcd = f & 7;
  const int i = f >> 3;
  const int bxPer = gx >> 3;
  by = i / bxPer;
  bx = xcd * bxPer + (i - by * bxPer);
}

// ---------------- GEMM: C[M,N] = A[M,K] * B[N,K]^T + bias ----------------
// BM x 128 tile, 4 waves (2x2), 16x16x32 bf16 MFMA.
// BK=64 (R10): single-buffer, 16*MI MFMA per barrier-pair + XOR-chunk
// swizzle (chunk ^= row&7) = min-cycle LDS banking. Swizzle on per-lane
// GLOBAL source (gload_lds dest linear, rule #21).
// BK=32 (R9): 2-phase dbuf, linear LDS — used by MLP1 (R12: reverted from
// BK=64 which coincided with the 405->411 regression).
// OUT_MODE: 0 = fp32 row-major, 1 = bf16 row-major,
//           3 = bf16 V^T direct [bh][e][2048] (fused transpose_v)
// SK: split-K (blockIdx.z); SK>1 -> fp32 atomicAdd, bias in slice 0.
template <int OUT_MODE, int BM, int SK, int BK>
__global__ __launch_bounds__(256) void gemm_bt(
    const bf16_t* __restrict__ A, const bf16_t* __restrict__ Bw,
    const float* __restrict__ bias, void* __restrict__ Cp,
    int M, int N, int K) {
  constexpr int MI = BM / 32;             // acc i-extent per wave
  constexpr bool DB = (BK == 32);         // double-buffer only BK=32 path
  constexpr int ASZ = BM * BK;
  constexpr int BSZ = 128 * BK;
  __shared__ bf16_t As[(DB ? 2 : 1) * ASZ];
  __shared__ bf16_t Bs[(DB ? 2 : 1) * BSZ];
  const int tid  = threadIdx.x;
  const int wave = tid >> 6, lane = tid & 63;
  const int quad = lane >> 4, l15 = lane & 15;
  int bx = blockIdx.x, by = blockIdx.y;
  xcd_chunk2d(bx, by);
  const int m0 = bx * BM, n0 = by * 128;
  const int wm = (wave >> 1) * (BM / 2), wn = (wave & 1) * 64;
  const int ks = (SK > 1) ? (int)blockIdx.z : 0;
  const int kbeg = ks * (K / SK), kend = kbeg + K / SK;

  floatx4 acc[MI][4] = {};

  if constexpr (BK == 32) {
    const int srowA = wave * (BM / 4) + (lane >> 2);
    const int srowB = wave * 32 + (lane >> 2);
    const int scol = (lane & 3) * 8;
    const bf16_t* Ag = A  + (size_t)(m0 + srowA) * K + scol;
    const bf16_t* Bg = Bw + (size_t)(n0 + srowB) * K + scol;
    auto stage = [&](int buf, int k0) {
      #pragma unroll
      for (int i = 0; i < BM / 64; ++i)
        GLD_LDS(Ag + (size_t)(i * 16) * K + k0,
                As + buf * ASZ + wave * (BM / 4) * 32 + i * 512);
      #pragma unroll
      for (int i = 0; i < 2; ++i)
        GLD_LDS(Bg + (size_t)(i * 16) * K + k0,
                Bs + buf * BSZ + wave * 1024 + i * 512);
    };
    stage(0, kbeg);
    __syncthreads();
    int cur = 0;
    for (int k0 = kbeg; k0 < kend; k0 += 32) {
      if (k0 + 32 < kend) stage(cur ^ 1, k0 + 32);
      bf16x8 af[MI], bfr[4];
      #pragma unroll
      for (int i = 0; i < MI; ++i)
        af[i] = *(const bf16x8*)(As + cur * ASZ + (wm + i * 16 + l15) * 32 + quad * 8);
      #pragma unroll
      for (int j = 0; j < 4; ++j)
        bfr[j] = *(const bf16x8*)(Bs + cur * BSZ + (wn + j * 16 + l15) * 32 + quad * 8);
      #pragma unroll
      for (int i = 0; i < MI; ++i)
        #pragma unroll
        for (int j = 0; j < 4; ++j)
          acc[i][j] = MFMA_BF16_16x16x32(af[i], bfr[j], acc[i][j], 0, 0, 0);
      __syncthreads();
      cur ^= 1;
    }
  } else {
    // BK=64 single-buffer, swizzled
    for (int k0 = kbeg; k0 < kend; k0 += 64) {
      __syncthreads();                    // all waves done reading prev tile
      #pragma unroll
      for (int i = 0; i < BM / 32; ++i) { // A: BM/4 rows/wave x 8 chunks
        const int flat = i * 64 + lane;
        const int rl = flat >> 3, ch = flat & 7;
        GLD_LDS(A + (size_t)(m0 + wave * (BM / 4) + rl) * K + k0 + ((ch ^ (rl & 7)) * 8),
                As + wave * (BM / 4) * 64 + i * 512);
      }
      #pragma unroll
      for (int i = 0; i < 4; ++i) {       // B: 32 rows/wave x 8 chunks
        const int flat = i * 64 + lane;
        const int rl = flat >> 3, ch = flat & 7;
        GLD_LDS(Bw + (size_t)(n0 + wave * 32 + rl) * K + k0 + ((ch ^ (rl & 7)) * 8),
                Bs + wave * 32 * 64 + i * 512);
      }
      __syncthreads();                    // drains vmcnt(0): tile resident
      #pragma unroll
      for (int kk = 0; kk < 2; ++kk) {
        const int co = ((quad + 4 * kk) ^ (l15 & 7)) * 8;
        bf16x8 af[MI], bfr[4];
        #pragma unroll
        for (int i = 0; i < MI; ++i)
          af[i] = *(const bf16x8*)(As + (wm + i * 16 + l15) * 64 + co);
        #pragma unroll
        for (int j = 0; j < 4; ++j)
          bfr[j] = *(const bf16x8*)(Bs + (wn + j * 16 + l15) * 64 + co);
        #pragma unroll
        for (int i = 0; i < MI; ++i)
          #pragma unroll
          for (int j = 0; j < 4; ++j)
            acc[i][j] = MFMA_BF16_16x16x32(af[i], bfr[j], acc[i][j], 0, 0, 0);
      }
    }
  }

  if (OUT_MODE == 3) {                    // fused V^T epilogue
    #pragma unroll
    for (int j = 0; j < 4; ++j) {
      const int col = n0 + wn + j * 16 + l15;
      const float bv = bias[col];
      const int h = col >> 6, e = col & 63;
      #pragma unroll
      for (int i = 0; i < MI; ++i) {
        const int row0 = m0 + wm + i * 16 + quad * 4;
        const int b = row0 >> 11, n = row0 & 2047;
        bf16x4 o;
        #pragma unroll
        for (int r = 0; r < 4; ++r) o[r] = (bf16_t)(acc[i][j][r] + bv);
        *(bf16x4*)((bf16_t*)Cp + ((size_t)((b << 4) + h) * 64 + e) * 2048 + n) = o;
      }
    }
    return;
  }
  #pragma unroll
  for (int j = 0; j < 4; ++j) {
    const int col = n0 + wn + j * 16 + l15;
    const float bv = (SK == 1 || ks == 0) ? bias[col] : 0.f;
    #pragma unroll
    for (int i = 0; i < MI; ++i) {
      #pragma unroll
      for (int r = 0; r < 4; ++r) {
        const int row = m0 + wm + i * 16 + quad * 4 + r;
        const float v = acc[i][j][r] + bv;
        if (OUT_MODE == 0) {
          if (SK > 1) atomicAdd(&((float*)Cp)[(size_t)row * N + col], v);
          else        ((float*)Cp)[(size_t)row * N + col] = v;
        } else if (OUT_MODE == 1) {
          ((bf16_t*)Cp)[(size_t)row * N + col] = (bf16_t)v;
        }
      }
    }
  }
}

// Split-precision GEMM for q,k: 3-term bf16 emulation of fp32.
// 64x128 tile, BK=64 single-buffer + XOR-chunk swizzle (R11, validated:
// dropped out of top-5). Writes q (cols<1024, scaled by 32*log2e — the
// exp2-rebase folds log2(e) into the QK^T product so attn softmax uses
// bare v_exp_f32) and k head-major, hi/lo.
__global__ __launch_bounds__(256) void gemm_qk_split(
    const bf16_t* __restrict__ Ah, const bf16_t* __restrict__ Al,
    const bf16_t* __restrict__ Bh, const bf16_t* __restrict__ Bl,
    const float* __restrict__ bias,
    bf16_t* __restrict__ qhi, bf16_t* __restrict__ qlo,
    bf16_t* __restrict__ khi, bf16_t* __restrict__ klo,
    int M, int N, int K) {
  __shared__ bf16_t Ash[64 * 64];
  __shared__ bf16_t Asl[64 * 64];
  __shared__ bf16_t Bsh[128 * 64];
  __shared__ bf16_t Bsl[128 * 64];
  const int tid  = threadIdx.x;
  const int wave = tid >> 6, lane = tid & 63;
  const int quad = lane >> 4, l15 = lane & 15;
  int bx = blockIdx.x, by = blockIdx.y;
  xcd_chunk2d(bx, by);
  const int m0 = bx * 64, n0 = by * 128;
  const int wm = (wave >> 1) * 32, wn = (wave & 1) * 64;

  floatx4 acc[2][4] = {};

  for (int k0 = 0; k0 < K; k0 += 64) {
    __syncthreads();                      // all waves done reading prev tile
    #pragma unroll
    for (int i = 0; i < 2; ++i) {         // A: 16 rows/wave x 8 chunks, hi+lo
      const int flat = i * 64 + lane;
      const int rl = flat >> 3, ch = flat & 7;
      const size_t off = (size_t)(m0 + wave * 16 + rl) * K + k0 + ((ch ^ (rl & 7)) * 8);
      GLD_LDS(Ah + off, Ash + wave * 16 * 64 + i * 512);
      GLD_LDS(Al + off, Asl + wave * 16 * 64 + i * 512);
    }
    #pragma unroll
    for (int i = 0; i < 4; ++i) {         // B: 32 rows/wave x 8 chunks, hi+lo
      const int flat = i * 64 + lane;
      const int rl = flat >> 3, ch = flat & 7;
      const size_t off = (size_t)(n0 + wave * 32 + rl) * K + k0 + ((ch ^ (rl & 7)) * 8);
      GLD_LDS(Bh + off, Bsh + wave * 32 * 64 + i * 512);
      GLD_LDS(Bl + off, Bsl + wave * 32 * 64 + i * 512);
    }
    __syncthreads();                      // drains vmcnt(0): tile resident
    #pragma unroll
    for (int kk = 0; kk < 2; ++kk) {
      const int co = ((quad + 4 * kk) ^ (l15 & 7)) * 8;
      bf16x8 ah[2], al[2], bh[4], bl[4];
      #pragma unroll
      for (int i = 0; i < 2; ++i) {
        const int ro = (wm + i * 16 + l15) * 64 + co;
        ah[i] = *(const bf16x8*)(Ash + ro);
        al[i] = *(const bf16x8*)(Asl + ro);
      }
      #pragma unroll
      for (int j = 0; j < 4; ++j) {
        const int ro = (wn + j * 16 + l15) * 64 + co;
        bh[j] = *(const bf16x8*)(Bsh + ro);
        bl[j] = *(const bf16x8*)(Bsl + ro);
      }
      #pragma unroll
      for (int i = 0; i < 2; ++i)
        #pragma unroll
        for (int j = 0; j < 4; ++j) {
          acc[i][j] = MFMA_BF16_16x16x32(ah[i], bh[j], acc[i][j], 0, 0, 0);
          acc[i][j] = MFMA_BF16_16x16x32(ah[i], bl[j], acc[i][j], 0, 0, 0);
          acc[i][j] = MFMA_BF16_16x16x32(al[i], bh[j], acc[i][j], 0, 0, 0);
        }
    }
  }
  #pragma unroll
  for (int j = 0; j < 4; ++j) {
    const int col = n0 + wn + j * 16 + l15;       // [0,2048)
    const float bv = bias[col];
    const bool isq = col < 1024;
    bf16_t* hib = isq ? qhi : khi;
    bf16_t* lob = isq ? qlo : klo;
    // q scale = sqrt(D) * log2(e) = 32 * 1.4426950409 (exp2 rebase)
    const float scale = isq ? 46.166241f : 1.0f;
    const int h = (col >> 6) & 15, e = col & 63;
    #pragma unroll
    for (int i = 0; i < 2; ++i) {
      #pragma unroll
      for (int r = 0; r < 4; ++r) {
        const int row = m0 + wm + i * 16 + quad * 4 + r;
        const int b = row >> 11, n = row & 2047;
        const float c = (acc[i][j][r] + bv) * scale;
        const bf16_t chi = (bf16_t)c;
        const bf16_t clo = (bf16_t)(c - (float)chi);
        const size_t dst = (((size_t)((b << 4) + h) * 2048 + n) << 6) + e;
        hib[dst] = chi;
        lob[dst] = clo;
      }
    }
  }
}

// ---------------- causal flash attention ----------------
// R12: VALU-bound fix (VALUBusy 39 > MfmaUtil 22). (a) exp2 rebase: QK^T
// is pre-scaled by log2e, so p = exp2f(s-m) = bare v_exp_f32 (saves 17
// v_mul/tile). (b) psum = P*ones via 2 MFMAs on the idle matrix pipe
// (replaces 16 serial adds + 2 shfl_xor); output is D-layout, so l_row
// lives as l_rowD[4] (rows quad*4+r) and the final 4 shuffles vanish.
// (c) tree-fmax. Swizzled 32KB LDS, (256,4), setprio unchanged.
#define SWZ(row, chunk) (((row) << 6) + ((((chunk) ^ ((row) & 7))) << 3))
__global__ __launch_bounds__(256, 4) void attn_causal(
    const bf16_t* __restrict__ qhi, const bf16_t* __restrict__ qlo,
    const bf16_t* __restrict__ khi, const bf16_t* __restrict__ klo,
    const bf16_t* __restrict__ vT, float* __restrict__ o) {
  __shared__ bf16_t KsH[64 * 64];     // [key][e], swizzled
  __shared__ bf16_t KsL[64 * 64];
  __shared__ bf16_t Vt[64 * 64];      // [e][key], swizzled
  __shared__ bf16_t Ps[4][16 * 64];   // per-wave P, rows=q (16), swizzled

  const int tid  = threadIdx.x;
  const int wave = tid >> 6, lane = tid & 63;
  const int quad = lane >> 4, l15 = lane & 15;
  const int bh = blockIdx.x;
  const int q0 = (31 - (int)blockIdx.y) * 64;    // heavy blocks first
  const size_t hb = (size_t)bh * 2048;

  // Q fragments: rows wmin+l15 (A/B-layout: row=l15, k=quad*8+j)
  const int wmin = q0 + wave * 16;
  const int qrow = wmin + l15;                   // this lane's q-row
  bf16x8 qh[2], ql[2];
  {
    const bf16_t* qbh = qhi + ((hb + wmin + l15) << 6) + quad * 8;
    const bf16_t* qbl = qlo + ((hb + wmin + l15) << 6) + quad * 8;
    qh[0] = *(const bf16x8*)qbh;
    qh[1] = *(const bf16x8*)(qbh + 32);
    ql[0] = *(const bf16x8*)qbl;
    ql[1] = *(const bf16x8*)(qbl + 32);
  }
  bf16x8 onesf;
  #pragma unroll
  for (int i = 0; i < 8; ++i) onesf[i] = (bf16_t)1.0f;

  floatx4 accO[4] = {};                // O[q=quad*4+r][e=j*16+l15]
  float m_row = -1e30f;                // running max (log2 dom) for row wmin+l15
  float l_rowD[4] = {};                // denom, D-layout rows wmin+quad*4+r

  // staging geometry: wave w covers rows [16w,16w+16) of K / e-rows of V^T
  const int kr = wave * 16 + (lane >> 3);     // + {0,8}
  const int kc7 = lane & 7;                   // 16B chunk index 0..7
  const bf16_t* kgh = khi + ((hb + kr) << 6) + kc7 * 8;
  const bf16_t* kgl = klo + ((hb + kr) << 6) + kc7 * 8;
  const bf16_t* vg  = vT + ((size_t)(bh * 64 + kr)) * 2048 + kc7 * 8;

  // prefetch tile 0
  bf16x8 pkh0 = *(const bf16x8*)(kgh);
  bf16x8 pkh1 = *(const bf16x8*)(kgh + (8 << 6));
  bf16x8 pkl0 = *(const bf16x8*)(kgl);
  bf16x8 pkl1 = *(const bf16x8*)(kgl + (8 << 6));
  bf16x8 pv0  = *(const bf16x8*)(vg);
  bf16x8 pv1  = *(const bf16x8*)(vg + 8 * 2048);

  const int ntiles = (q0 >> 6) + 1;
  for (int t = 0; t < ntiles; ++t) {
    const int k0 = t * 64;
    __syncthreads();                          // all waves done reading prev LDS
    *(bf16x8*)(KsH + SWZ(kr, kc7))     = pkh0;
    *(bf16x8*)(KsH + SWZ(kr + 8, kc7)) = pkh1;
    *(bf16x8*)(KsL + SWZ(kr, kc7))     = pkl0;
    *(bf16x8*)(KsL + SWZ(kr + 8, kc7)) = pkl1;
    *(bf16x8*)(Vt  + SWZ(kr, kc7))     = pv0;
    *(bf16x8*)(Vt  + SWZ(kr + 8, kc7)) = pv1;
    if (t + 1 < ntiles) {                     // prefetch next tile
      const int koff = (t + 1) << 12;         // 64 rows * 64 el (K layout)
      pkh0 = *(const bf16x8*)(kgh + koff);
      pkh1 = *(const bf16x8*)(kgh + koff + (8 << 6));
      pkl0 = *(const bf16x8*)(kgl + koff);
      pkl1 = *(const bf16x8*)(kgl + koff + (8 << 6));
      pv0  = *(const bf16x8*)(vg + (t + 1) * 64);
      pv1  = *(const bf16x8*)(vg + (t + 1) * 64 + 8 * 2048);
    }
    __syncthreads();                          // staging visible

    const bool needmask = (k0 + 63 > wmin);

    // S^T = K Q^T (split 3-term): lane holds S[key=k0+j*16+quad*4+r][qrow]
    floatx4 sv[4];
    __builtin_amdgcn_s_setprio(1);
    #pragma unroll
    for (int j = 0; j < 4; ++j) {
      const int rK = j * 16 + l15;
      const bf16x8 kh0 = *(const bf16x8*)(KsH + SWZ(rK, quad));
      const bf16x8 kh1 = *(const bf16x8*)(KsH + SWZ(rK, quad + 4));
      const bf16x8 kl0 = *(const bf16x8*)(KsL + SWZ(rK, quad));
      const bf16x8 kl1 = *(const bf16x8*)(KsL + SWZ(rK, quad + 4));
      floatx4 acc = {};
      acc = MFMA_BF16_16x16x32(kh0, qh[0], acc, 0, 0, 0);
      acc = MFMA_BF16_16x16x32(kh1, qh[1], acc, 0, 0, 0);
      acc = MFMA_BF16_16x16x32(kl0, qh[0], acc, 0, 0, 0);
      acc = MFMA_BF16_16x16x32(kl1, qh[1], acc, 0, 0, 0);
      acc = MFMA_BF16_16x16x32(kh0, ql[0], acc, 0, 0, 0);
      acc = MFMA_BF16_16x16x32(kh1, ql[1], acc, 0, 0, 0);
      sv[j] = acc;
    }
    __builtin_amdgcn_s_setprio(0);

    // in-lane softmax (log2 domain) for q-row wmin+l15; keys j*16+quad*4+r
    const int lim = qrow - k0 - quad * 4;     // mask if j*16+r > lim
    float mj[4];
    #pragma unroll
    for (int j = 0; j < 4; ++j) {
      #pragma unroll
      for (int r = 0; r < 4; ++r) {
        float x = sv[j][r];
        if (needmask && (j * 16 + r > lim)) x = -1e30f;
        sv[j][r] = x;
      }
      mj[j] = fmaxf(fmaxf(sv[j][0], sv[j][1]), fmaxf(sv[j][2], sv[j][3]));
    }
    float mr = fmaxf(fmaxf(mj[0], mj[1]), fmaxf(mj[2], mj[3]));
    mr = fmaxf(mr, __shfl_xor(mr, 16));       // reduce across quads
    mr = fmaxf(mr, __shfl_xor(mr, 32));
    const float mold = m_row;
    const float mnew = fmaxf(mold, mr);
    m_row = mnew;
    bf16x4 pb[4];
    #pragma unroll
    for (int j = 0; j < 4; ++j)
      #pragma unroll
      for (int r = 0; r < 4; ++r)
        pb[j][r] = (bf16_t)exp2f(sv[j][r] - mnew);
    // write P^T -> A-layout rows: Ps[qlocal=l15][key j*16+quad*4 .. +3]
    {
      bf16_t* pw = &Ps[wave][0];
      #pragma unroll
      for (int j = 0; j < 4; ++j)
        *(bf16x4*)(pw + SWZ(l15, 2 * j + (quad >> 1)) + (quad & 1) * 4) = pb[j];
    }
    const float alpha = exp2f(mold - mnew);   // ==1 when no max growth
    // Ps is wave-private: LDS completion is enough, no block barrier
    asm volatile("s_waitcnt lgkmcnt(0)" ::: "memory");
    __builtin_amdgcn_sched_barrier(0);

    // read back P fragments (A-layout rows l15)
    bf16x8 pf[2];
    {
      const bf16_t* pw = &Ps[wave][0];
      pf[0] = *(const bf16x8*)(pw + SWZ(l15, quad));
      pf[1] = *(const bf16x8*)(pw + SWZ(l15, quad + 4));
    }
    // psum via ones-MFMA: ps[r] = sum_k P[row quad*4+r][k] (D-layout),
    // summing the same bf16 values as the PV numerator.
    floatx4 ps = {};
    ps = MFMA_BF16_16x16x32(pf[0], onesf, ps, 0, 0, 0);
    ps = MFMA_BF16_16x16x32(pf[1], onesf, ps, 0, 0, 0);
    if (__any(mnew > mold)) {                 // defer-rescale when max static
      #pragma unroll
      for (int r = 0; r < 4; ++r) {
        const float ar = __shfl(alpha, quad * 4 + r);  // alpha of row quad*4+r
        l_rowD[r] = l_rowD[r] * ar + ps[r];
        #pragma unroll
        for (int j = 0; j < 4; ++j) accO[j][r] *= ar;
      }
    } else {
      #pragma unroll
      for (int r = 0; r < 4; ++r) l_rowD[r] += ps[r];
    }

    // O += P V   (P: A-layout rows l15; V^T: B-layout from Vt)
    __builtin_amdgcn_s_setprio(1);
    #pragma unroll
    for (int j = 0; j < 4; ++j) {
      const int rV = j * 16 + l15;
      const bf16x8 vf0 = *(const bf16x8*)(Vt + SWZ(rV, quad));
      const bf16x8 vf1 = *(const bf16x8*)(Vt + SWZ(rV, quad + 4));
      accO[j] = MFMA_BF16_16x16x32(pf[0], vf0, accO[j], 0, 0, 0);
      accO[j] = MFMA_BF16_16x16x32(pf[1], vf1, accO[j], 0, 0, 0);
    }
    __builtin_amdgcn_s_setprio(0);
  }

  // normalize + write (token-major fp32 for resid_ln); l_rowD is already
  // in D-layout -> no shuffles.
  const int b = bh >> 4, h = bh & 15;
  #pragma unroll
  for (int r = 0; r < 4; ++r) {
    const float linv = 1.f / l_rowD[r];
    const int qr = wmin + quad * 4 + r;
    float* orow = o + ((size_t)(b * 2048) + qr) * 1024 + h * 64;
    #pragma unroll
    for (int j = 0; j < 4; ++j)
      orow[j * 16 + l15] = accO[j][r] * linv;
  }
}

// ---------------- launcher ----------------

extern "C" void kernel_launch(void* const* d_in, const int* in_sizes, int n_in,
                              void* d_out, int out_size, void* d_ws, size_t ws_size,
                              hipStream_t stream) {
  const float* x        = (const float*)d_in[0];
  const float* wq       = (const float*)d_in[1];
  const float* bq       = (const float*)d_in[2];
  const float* wk       = (const float*)d_in[3];
  const float* bk       = (const float*)d_in[4];
  const float* wv       = (const float*)d_in[5];
  const float* bv       = (const float*)d_in[6];
  const float* w1       = (const float*)d_in[7];
  const float* b1       = (const float*)d_in[8];
  const float* ln_mlp_g = (const float*)d_in[9];
  const float* ln_mlp_b = (const float*)d_in[10];
  const float* w2       = (const float*)d_in[11];
  const float* b2       = (const float*)d_in[12];
  const float* ln1_g    = (const float*)d_in[13];
  const float* ln1_b    = (const float*)d_in[14];
  const float* ln2_g    = (const float*)d_in[15];
  const float* ln2_b    = (const float*)d_in[16];

  char* ws = (char*)d_ws;
  bf16_t* h_hi   = (bf16_t*)(ws);                  // 8 MiB  [4096,1024]
  bf16_t* h_lo   = (bf16_t*)(ws + (8u  << 20));    // 8 MiB
  bf16_t* wqk_hi = (bf16_t*)(ws + (16u << 20));    // 4 MiB  [2048,1024]
  bf16_t* wqk_lo = (bf16_t*)(ws + (20u << 20));    // 4 MiB
  bf16_t* wvb    = (bf16_t*)(ws + (24u << 20));    // 2 MiB  [1024,1024]
  float*  bqk    = (float*) (ws + (26u << 20));    // 8 KiB  [2048]
  bf16_t* w1b    = (bf16_t*)(ws + (28u << 20));    // 8 MiB  [4096,1024]
  bf16_t* w2b    = (bf16_t*)(ws + (36u << 20));    // 8 MiB  [1024,4096]
  bf16_t* qhi    = (bf16_t*)(ws + (44u << 20));    // 8 MiB  [32,2048,64] head-major
  bf16_t* qlo    = (bf16_t*)(ws + (52u << 20));    // 8 MiB
  bf16_t* khi    = (bf16_t*)(ws + (60u << 20));    // 8 MiB
  bf16_t* klo    = (bf16_t*)(ws + (68u << 20));    // 8 MiB
  bf16_t* mbuf   = (bf16_t*)(ws + (44u << 20));    // 32 MiB [4096,4096] (aliases q/k; dead by MLP1)
  bf16_t* vTb    = (bf16_t*)(ws + (76u << 20));    // 8 MiB  [32,64,2048] V^T (written directly by gemm_bt<3>)
  float*  attnb  = (float*) (ws + (84u << 20));    // 16 MiB [4096,1024] fp32
  bf16_t* h2     = (bf16_t*)(ws + (100u << 20));   // 8 MiB  -> total 108 MiB

  // zero d_out for split-K atomic accumulation (capture-safe async memset)
  hipMemsetAsync(d_out, 0, (size_t)4096 * 1024 * sizeof(float), stream);

  prep<<<11268, 256, 0, stream>>>(wq, wk, wv, w1, w2, bq, bk,
                                  wqk_hi, wqk_lo, wvb, w1b, w2b, bqk);

  ln_fwd_split<<<4096, 256, 0, stream>>>(x, ln1_g, ln1_b, h_hi, h_lo);
  gemm_qk_split<<<dim3(64, 16), 256, 0, stream>>>(h_hi, h_lo, wqk_hi, wqk_lo, bqk,
                                                  qhi, qlo, khi, klo, 4096, 2048, 1024);
  gemm_bt<3, 64, 1, 64><<<dim3(64, 8), 256, 0, stream>>>(h_hi, wvb, bv, vTb, 4096, 1024, 1024);
  attn_causal<<<dim3(32, 32), 256, 0, stream>>>(qhi, qlo, khi, klo, vTb, attnb);
  resid_ln_fwd<<<4096, 256, 0, stream>>>(x, attnb, ln2_g, ln2_b, h2);
  gemm_bt<1, 128, 1, 32><<<dim3(32, 32), 256, 0, stream>>>(h2, w1b, b1, mbuf, 4096, 4096, 1024);
  ln_relu_inplace<<<4096, 256, 0, stream>>>(mbuf, ln_mlp_g, ln_mlp_b);
  gemm_bt<0, 64, 2, 64><<<dim3(64, 8, 2), 256, 0, stream>>>(mbuf, w2b, b2, d_out, 4096, 1024, 4096);

  (void)in_sizes; (void)n_in; (void)out_size; (void)ws_size;
}